// Round 2
// 762.791 us; speedup vs baseline: 1.0770x; 1.0770x over previous
//
#include <hip/hip_runtime.h>

#define N_NODES 50000
#define N_EDGES 800000
#define HROW 72   // u16 row stride for LDS H tiles

typedef unsigned short u16;
typedef __attribute__((ext_vector_type(8))) short short8;
typedef __attribute__((ext_vector_type(4))) float f32x4;

#define MFMA16(a, b, c) __builtin_amdgcn_mfma_f32_16x16x32_bf16((a), (b), (c), 0, 0, 0)

__device__ __forceinline__ float b2f(u16 u) {
    union { unsigned int i; float f; } v; v.i = ((unsigned int)u) << 16; return v.f;
}
__device__ __forceinline__ u16 f2b(float f) {
    union { float f; unsigned int i; } v; v.f = f;
    unsigned int x = v.i;
    return (u16)((x + 0x7fffu + ((x >> 16) & 1u)) >> 16);
}
// packed RNE f32x2 -> bf16x2 via HW cvt (bit-identical to f2b for finite values)
__device__ __forceinline__ unsigned int f2b2(float a, float b) {
    unsigned int r;
    asm("v_cvt_pk_bf16_f32 %0, %1, %2" : "=v"(r) : "v"(a), "v"(b));
    return r;
}
__device__ __forceinline__ short8 cvt8(const float* p) {
    const float4 a = *(const float4*)p;
    const float4 b = *(const float4*)(p + 4);
    union { unsigned int u[4]; short8 s; } r;
    r.u[0] = f2b2(a.x, a.y); r.u[1] = f2b2(a.z, a.w);
    r.u[2] = f2b2(b.x, b.y); r.u[3] = f2b2(b.z, b.w);
    return r.s;
}

// ---- setup: fp32->bf16 node convert + dst histogram (merged) ----------------
__global__ void setup_cvt_hist(const float* __restrict__ node_h, u16* __restrict__ hbuf,
                               const int* __restrict__ dst, int* __restrict__ deg) {
    const int i = blockIdx.x * 256 + threadIdx.x;
    if (i < N_EDGES) atomicAdd(&deg[dst[i]], 1);
    if (i < N_NODES * 8) *(short8*)&hbuf[i * 8] = cvt8(&node_h[i * 8]);
}
__global__ void csr_scan(const int* __restrict__ deg, int* __restrict__ off,
                         int* __restrict__ cur) {
    __shared__ int tot[1024];
    const int t = threadIdx.x;
    const int beg = t * 49;
    const int end = (beg + 49 < N_NODES) ? beg + 49 : N_NODES;
    int s = 0;
    for (int i = beg; i < end; ++i) s += deg[i];
    tot[t] = s;
    __syncthreads();
    for (int d = 1; d < 1024; d <<= 1) {
        const int v = (t >= d) ? tot[t - d] : 0;
        __syncthreads();
        tot[t] += v;
        __syncthreads();
    }
    int run = tot[t] - s;
    for (int i = beg; i < end; ++i) { const int d = deg[i]; off[i] = run; cur[i] = run; run += d; }
    if (t == 1023) off[N_NODES] = tot[1023];
}
__global__ void csr_scatter(const int* __restrict__ src, const int* __restrict__ dst,
                            int* __restrict__ cur, int* __restrict__ eidx,
                            int* __restrict__ ssrc, int* __restrict__ sdst) {
    const int e = blockIdx.x * 256 + threadIdx.x;
    if (e < N_EDGES) {
        const int d = dst[e];
        const int p = atomicAdd(&cur[d], 1);
        eidx[p] = e; ssrc[p] = src[e]; sdst[p] = d;
    }
}

// ---- one-shot weight swizzle (all layers, edge + node) into frag order ------
// With the swapped-operand MFMA (Y^T = W^T * X^T), the A-frag map for W^T is
// identical to the old B-frag map for W:
// value at (lane,j) = W[ks*32+(lane>>4)*8+j][nt*16+(lane&15)].
__global__ void swizzle_all(const float* __restrict__ eW0, const float* __restrict__ eW1,
                            const float* __restrict__ eW2, const float* __restrict__ eW3,
                            const float* __restrict__ nW0, const float* __restrict__ nW1,
                            const float* __restrict__ nW2, const float* __restrict__ nW3,
                            u16* __restrict__ eswz, u16* __restrict__ nswz)
{
    const int ETOT = 3 * 12 * 2048, NTOT = 3 * 10 * 2048;
    for (int idx = blockIdx.x * 256 + threadIdx.x; idx < ETOT + NTOT; idx += gridDim.x * 256) {
        const bool isE = idx < ETOT;
        const int id = isE ? idx : idx - ETOT;
        const int per = isE ? 12 * 2048 : 10 * 2048;
        const int l = id / per, rem = id % per;
        const int t = rem >> 11;
        const int r2 = rem & 2047;
        const int nt = r2 >> 9, lane = (r2 >> 3) & 63, j = r2 & 7;
        const int ks0 = isE ? 6 : 4;
        const float* W; int ks;
        if (t < ks0) {
            W = (isE ? eW0 : nW0) + (size_t)l * (isE ? 192 * 64 : 128 * 64);
            ks = t;
        } else {
            const int u = t - ks0;
            const float* Wb = isE ? (u < 2 ? eW1 : (u < 4 ? eW2 : eW3))
                                  : (u < 2 ? nW1 : (u < 4 ? nW2 : nW3));
            W = Wb + (size_t)l * 4096; ks = u & 1;
        }
        const int k = ks * 32 + (lane >> 4) * 8 + j;
        const int n = nt * 16 + (lane & 15);
        const u16 v = f2b(W[k * 64 + n]);
        if (isE) eswz[id] = v; else nswz[id] = v;
    }
}

// ===================== edge pass + fused dst aggregation =====================
// Swapped-operand MFMA: acc = W^T-frag * X-frag  =>  lane (col,q) holds
// Y[edge col][features nt*16+q*4 .. +3] per nt  =>  packed b64 LDS writes,
// register-direct e_sorted stores, pk-cvt epilogue.
// MODE 0: first layer — gather fp32 edge_h via eidx (perm_edge eliminated), store e
// MODE 1: middle     — read bf16 e_sorted, store e
// MODE 2: last       — read bf16 e_sorted, skip dead e store
template<int MODE>
__global__ __launch_bounds__(512, 4)
void edge_pass(const u16* __restrict__ h16,
               u16* __restrict__ e_sorted,
               const float* __restrict__ e32, const int* __restrict__ eidx,
               const int* __restrict__ ssrc, const int* __restrict__ sdst,
               const u16* __restrict__ wz,
               const float* __restrict__ b0, const float* __restrict__ b1,
               const float* __restrict__ b2, const float* __restrict__ b3,
               float* __restrict__ agg)
{
    __shared__ __align__(16) u16 w0s[6 * 2048];      // 24 KB
    __shared__ __align__(16) u16 w1s[3 * 2 * 2048];  // 24 KB
    __shared__ __align__(16) float biasS[256];
    __shared__ __align__(16) u16 hb[8 * 16 * HROW];  // 18 KB
    __shared__ int dstS[8][16];

    const int tid = threadIdx.x;
    {
        const uint4* s = (const uint4*)wz;
        uint4* dA = (uint4*)w0s; uint4* dB = (uint4*)w1s;
        #pragma unroll
        for (int i = 0; i < 3; ++i) dA[tid + i * 512] = s[tid + i * 512];
        #pragma unroll
        for (int i = 0; i < 3; ++i) dB[tid + i * 512] = s[1536 + tid + i * 512];
        if (tid < 256) {
            const int which = tid >> 6, j = tid & 63;
            const float* bp = (which == 0) ? b0 : (which == 1) ? b1 : (which == 2) ? b2 : b3;
            biasS[tid] = bp[j];
        }
    }
    __syncthreads();  // only barrier

    const int w = tid >> 6, lane = tid & 63, col = lane & 15, q = lane >> 4;
    u16* hw = &hb[w * 16 * HROW];
    const int nT = N_EDGES / 128;
    const int G = gridDim.x;

#define LOAD_AF(dst_, sv_, tv_, j_, ei_)                                        \
    dst_[0] = *(const short8*)&h16[(size_t)(sv_) * 64 + q * 8];                 \
    dst_[1] = *(const short8*)&h16[(size_t)(sv_) * 64 + 32 + q * 8];            \
    dst_[2] = *(const short8*)&h16[(size_t)(tv_) * 64 + q * 8];                 \
    dst_[3] = *(const short8*)&h16[(size_t)(tv_) * 64 + 32 + q * 8];            \
    if (MODE == 0) {                                                            \
        const float* ep_ = e32 + (size_t)(ei_) * 64 + q * 8;                    \
        dst_[4] = cvt8(ep_);                                                    \
        dst_[5] = cvt8(ep_ + 32);                                               \
    } else {                                                                    \
        dst_[4] = *(const short8*)&e_sorted[(size_t)(j_) * 64 + q * 8];         \
        dst_[5] = *(const short8*)&e_sorted[(size_t)(j_) * 64 + 32 + q * 8];    \
    }

    // prologue: tile t fragments + tile t+G indices
    int t = blockIdx.x;
    int j0 = t * 128 + w * 16 + col;
    int sv0 = ssrc[j0], tv0 = sdst[j0];
    int ei0 = (MODE == 0) ? eidx[j0] : 0;
    short8 af[6];
    LOAD_AF(af, sv0, tv0, j0, ei0)
    int t1 = t + G, j1 = 0, sv1 = 0, tv1 = 0, ei1 = 0;
    if (t1 < nT) {
        j1 = t1 * 128 + w * 16 + col; sv1 = ssrc[j1]; tv1 = sdst[j1];
        if (MODE == 0) ei1 = eidx[j1];
    }

    for (; t < nT; ) {
        // prefetch next tile's fragments (indices loaded last iteration)
        short8 afn[6];
        if (t1 < nT) { LOAD_AF(afn, sv1, tv1, j1, ei1) }
        // prefetch indices two tiles ahead
        const int t2 = t1 + G;
        int j2 = 0, sv2 = 0, tv2 = 0, ei2 = 0;
        if (t2 < nT) {
            j2 = t2 * 128 + w * 16 + col; sv2 = ssrc[j2]; tv2 = sdst[j2];
            if (MODE == 0) ei2 = eidx[j2];
        }

        // publish this tile's dst list for the fused reduce
        if (q == 0) dstS[w][col] = tv0;

        // ---- layer 1: K=192, swapped operands ----
        #pragma unroll
        for (int nt = 0; nt < 4; ++nt) {
            f32x4 acc = {0.f, 0.f, 0.f, 0.f};
            #pragma unroll
            for (int ks = 0; ks < 6; ++ks)
                acc = MFMA16(*(const short8*)&w0s[(ks * 4 + nt) * 512 + lane * 8], af[ks], acc);
            const float4 bv = *(const float4*)&biasS[nt * 16 + q * 4];
            uint2 pk;
            pk.x = f2b2(fmaxf(acc[0] + bv.x, 0.f), fmaxf(acc[1] + bv.y, 0.f));
            pk.y = f2b2(fmaxf(acc[2] + bv.z, 0.f), fmaxf(acc[3] + bv.w, 0.f));
            *(uint2*)&hw[col * HROW + nt * 16 + q * 4] = pk;
        }
        // ---- layers 2..4: K=64 ----
        #pragma unroll
        for (int li = 0; li < 3; ++li) {
            const short8 ah0 = *(const short8*)&hw[col * HROW + q * 8];
            const short8 ah1 = *(const short8*)&hw[col * HROW + 32 + q * 8];
            const u16* wls = &w1s[li * 4096];
            #pragma unroll
            for (int nt = 0; nt < 4; ++nt) {
                f32x4 acc = {0.f, 0.f, 0.f, 0.f};
                acc = MFMA16(*(const short8*)&wls[nt * 512 + lane * 8], ah0, acc);
                acc = MFMA16(*(const short8*)&wls[(4 + nt) * 512 + lane * 8], ah1, acc);
                const float4 bv = *(const float4*)&biasS[(li + 1) * 64 + nt * 16 + q * 4];
                uint2 pk;
                pk.x = f2b2(fmaxf(acc[0] + bv.x, 0.f), fmaxf(acc[1] + bv.y, 0.f));
                pk.y = f2b2(fmaxf(acc[2] + bv.z, 0.f), fmaxf(acc[3] + bv.w, 0.f));
                *(uint2*)&hw[col * HROW + nt * 16 + q * 4] = pk;
                if (li == 2 && MODE != 2)   // register-direct e store; dead on last layer
                    *(uint2*)&e_sorted[(size_t)(t * 128 + w * 16 + col) * 64 + nt * 16 + q * 4] = pk;
            }
        }
        // ---- fused segmented reduce: lane = column, walk 16 dst-sorted rows --
        {
            float racc = 0.f;
            int curd = dstS[w][0];
            #pragma unroll
            for (int r = 0; r < 16; ++r) {
                const float v = b2f(hw[r * HROW + lane]);
                const int d = dstS[w][r];        // wave-uniform broadcast
                if (d != curd) {                 // wave-uniform branch
                    atomicAdd(&agg[(size_t)curd * 64 + lane], racc);
                    racc = 0.f; curd = d;
                }
                racc += v;
            }
            atomicAdd(&agg[(size_t)curd * 64 + lane], racc);
        }
        // rotate pipeline
        #pragma unroll
        for (int i = 0; i < 6; ++i) af[i] = afn[i];
        t = t1; t1 = t2;
        j0 = j1; sv0 = sv1; tv0 = tv1; ei0 = ei1;
        j1 = j2; sv1 = sv2; tv1 = tv2; ei1 = ei2;
    }
#undef LOAD_AF
}

// ===================== node MLP (swapped-operand MFMA) =======================
__global__ __launch_bounds__(512, 4)
void node_mlp(float* __restrict__ agg,
              const u16* __restrict__ h16,
              const u16* __restrict__ wz,
              const float* __restrict__ b0, const float* __restrict__ b1,
              const float* __restrict__ b2, const float* __restrict__ b3,
              u16* __restrict__ hout16, float* __restrict__ hout32)
{
    __shared__ __align__(16) u16 w0s[4 * 2048];      // 16 KB
    __shared__ __align__(16) u16 w1s[3 * 2 * 2048];  // 24 KB
    __shared__ __align__(16) float biasS[256];
    __shared__ __align__(16) u16 hb[8 * 16 * HROW];

    const int tid = threadIdx.x;
    {
        const uint4* s = (const uint4*)wz;
        uint4* dA = (uint4*)w0s; uint4* dB = (uint4*)w1s;
        #pragma unroll
        for (int i = 0; i < 2; ++i) dA[tid + i * 512] = s[tid + i * 512];
        #pragma unroll
        for (int i = 0; i < 3; ++i) dB[tid + i * 512] = s[1024 + tid + i * 512];
        if (tid < 256) {
            const int which = tid >> 6, j = tid & 63;
            const float* bp = (which == 0) ? b0 : (which == 1) ? b1 : (which == 2) ? b2 : b3;
            biasS[tid] = bp[j];
        }
    }
    __syncthreads();

    const int w = tid >> 6, lane = tid & 63, col = lane & 15, q = lane >> 4;
    u16* hw = &hb[w * 16 * HROW];
    const int base = blockIdx.x * 128 + w * 16;

    const int nm = base + col;
    const int nmc = (nm < N_NODES) ? nm : 0;
    short8 af[4];
    af[0] = cvt8(&agg[(size_t)nmc * 64 + q * 8]);
    af[1] = cvt8(&agg[(size_t)nmc * 64 + 32 + q * 8]);
    af[2] = *(const short8*)&h16[(size_t)nmc * 64 + q * 8];
    af[3] = *(const short8*)&h16[(size_t)nmc * 64 + 32 + q * 8];

    // zero agg for the next layer's atomics (skip on final layer — dead)
    if (!hout32 && nm < N_NODES) {
        const float4 z = {0.f, 0.f, 0.f, 0.f};
        *(float4*)&agg[(size_t)nm * 64 + q * 8]          = z;
        *(float4*)&agg[(size_t)nm * 64 + q * 8 + 4]      = z;
        *(float4*)&agg[(size_t)nm * 64 + 32 + q * 8]     = z;
        *(float4*)&agg[(size_t)nm * 64 + 32 + q * 8 + 4] = z;
    }

    // ---- layer 1: K=128 ----
    #pragma unroll
    for (int nt = 0; nt < 4; ++nt) {
        f32x4 acc = {0.f, 0.f, 0.f, 0.f};
        #pragma unroll
        for (int ks = 0; ks < 4; ++ks)
            acc = MFMA16(*(const short8*)&w0s[(ks * 4 + nt) * 512 + lane * 8], af[ks], acc);
        const float4 bv = *(const float4*)&biasS[nt * 16 + q * 4];
        uint2 pk;
        pk.x = f2b2(fmaxf(acc[0] + bv.x, 0.f), fmaxf(acc[1] + bv.y, 0.f));
        pk.y = f2b2(fmaxf(acc[2] + bv.z, 0.f), fmaxf(acc[3] + bv.w, 0.f));
        *(uint2*)&hw[col * HROW + nt * 16 + q * 4] = pk;
    }
    // ---- layers 2..4 ----
    #pragma unroll
    for (int li = 0; li < 3; ++li) {
        const short8 ah0 = *(const short8*)&hw[col * HROW + q * 8];
        const short8 ah1 = *(const short8*)&hw[col * HROW + 32 + q * 8];
        const u16* wls = &w1s[li * 4096];
        #pragma unroll
        for (int nt = 0; nt < 4; ++nt) {
            f32x4 acc = {0.f, 0.f, 0.f, 0.f};
            acc = MFMA16(*(const short8*)&wls[nt * 512 + lane * 8], ah0, acc);
            acc = MFMA16(*(const short8*)&wls[(4 + nt) * 512 + lane * 8], ah1, acc);
            const float4 bv = *(const float4*)&biasS[(li + 1) * 64 + nt * 16 + q * 4];
            const float v0 = fmaxf(acc[0] + bv.x, 0.f);
            const float v1 = fmaxf(acc[1] + bv.y, 0.f);
            const float v2 = fmaxf(acc[2] + bv.z, 0.f);
            const float v3 = fmaxf(acc[3] + bv.w, 0.f);
            if (li < 2) {
                uint2 pk; pk.x = f2b2(v0, v1); pk.y = f2b2(v2, v3);
                *(uint2*)&hw[col * HROW + nt * 16 + q * 4] = pk;
            } else if (hout32) {           // final GNN layer: fp32 out, register-direct
                if (nm < N_NODES) {
                    const float4 o = {v0, v1, v2, v3};
                    *(float4*)&hout32[(size_t)nm * 64 + nt * 16 + q * 4] = o;
                }
            } else {                       // intermediate GNN layer: bf16 h, register-direct
                if (nm < N_NODES) {
                    uint2 pk; pk.x = f2b2(v0, v1); pk.y = f2b2(v2, v3);
                    *(uint2*)&hout16[(size_t)nm * 64 + nt * 16 + q * 4] = pk;
                }
            }
        }
    }
}

extern "C" void kernel_launch(void* const* d_in, const int* in_sizes, int n_in,
                              void* d_out, int out_size, void* d_ws, size_t ws_size,
                              hipStream_t stream)
{
    const float* node_h = (const float*)d_in[0];
    const float* edge_h = (const float*)d_in[1];
    const int* src      = (const int*)d_in[2];
    const int* dst      = (const int*)d_in[3];
    const float* eW[4] = {(const float*)d_in[4],  (const float*)d_in[8],
                          (const float*)d_in[12], (const float*)d_in[16]};
    const float* eb[4] = {(const float*)d_in[5],  (const float*)d_in[9],
                          (const float*)d_in[13], (const float*)d_in[17]};
    const float* nW[4] = {(const float*)d_in[6],  (const float*)d_in[10],
                          (const float*)d_in[14], (const float*)d_in[18]};
    const float* nb[4] = {(const float*)d_in[7],  (const float*)d_in[11],
                          (const float*)d_in[15], (const float*)d_in[19]};

    // ws layout
    u16* ebuf   = (u16*)d_ws;                            // e_sorted: 51.2M u16
    u16* hbuf   = ebuf + (size_t)N_EDGES * 64;           // 3.2M u16
    float* agg  = (float*)(hbuf + (size_t)N_NODES * 64); // 3.2M f32
    u16* eswz   = (u16*)(agg + (size_t)N_NODES * 64);    // 73728 u16
    u16* nswz   = eswz + 3 * 24576;                      // 61440 u16
    int* off    = (int*)(nswz + 3 * 20480);              // N+1
    int* cur    = off + (N_NODES + 4);
    int* deg    = cur + N_NODES;
    int* eidx   = deg + N_NODES;                         // E
    int* ssrc   = eidx + N_EDGES;                        // E
    int* sdst   = ssrc + N_EDGES;                        // E

    // one-time per launch
    hipMemsetAsync(deg, 0, N_NODES * sizeof(int), stream);
    hipMemsetAsync(agg, 0, (size_t)N_NODES * 64 * sizeof(float), stream);
    setup_cvt_hist<<<(N_EDGES + 255) / 256, 256, 0, stream>>>(node_h, hbuf, dst, deg);
    csr_scan<<<1, 1024, 0, stream>>>(deg, off, cur);
    csr_scatter<<<(N_EDGES + 255) / 256, 256, 0, stream>>>(src, dst, cur, eidx, ssrc, sdst);
    swizzle_all<<<528, 256, 0, stream>>>(eW[0], eW[1], eW[2], eW[3],
                                         nW[0], nW[1], nW[2], nW[3], eswz, nswz);

    for (int l = 0; l < 3; ++l) {
        const u16* wzl = eswz + (size_t)l * 24576;
        const float* bb0 = eb[0] + l * 64, *bb1 = eb[1] + l * 64,
                   * bb2 = eb[2] + l * 64, *bb3 = eb[3] + l * 64;
        if (l == 0)
            edge_pass<0><<<512, 512, 0, stream>>>(hbuf, ebuf, edge_h, eidx, ssrc, sdst,
                                                  wzl, bb0, bb1, bb2, bb3, agg);
        else if (l == 1)
            edge_pass<1><<<512, 512, 0, stream>>>(hbuf, ebuf, nullptr, nullptr, ssrc, sdst,
                                                  wzl, bb0, bb1, bb2, bb3, agg);
        else
            edge_pass<2><<<512, 512, 0, stream>>>(hbuf, ebuf, nullptr, nullptr, ssrc, sdst,
                                                  wzl, bb0, bb1, bb2, bb3, agg);
        node_mlp<<<(N_NODES + 127) / 128, 512, 0, stream>>>(
            agg, hbuf, nswz + (size_t)l * 20480,
            nb[0] + l * 64, nb[1] + l * 64, nb[2] + l * 64, nb[3] + l * 64,
            (l < 2) ? hbuf : nullptr, (l == 2) ? (float*)d_out : nullptr);
    }
}